// Round 7
// baseline (337.845 us; speedup 1.0000x reference)
//
#include <hip/hip_runtime.h>
#include <hip/hip_bf16.h>

#define M_DIM 64
#define K_DIM 4096
#define N_DIM 14336
#define NBLKS 256       // one block per 56 n-cols (14336 = 256*56) -> 100% CU
#define WPB 56          // cols per block
#define KW 512          // k-range per wave (8 waves cover K=4096)
#define WCHUNKS 16      // 32-k chunks per wave

typedef __attribute__((ext_vector_type(8))) short bf16x8;
typedef __attribute__((ext_vector_type(4))) float f32x4;
typedef unsigned short u16;

// ---------------------------------------------------------------------------
// prep v3 (proven): pure split of x (fp32) into bf16 hi/lo in MFMA-A-fragment
// layout (elem idx = (k/8)*(64*8) + m*8 + (k%8)). 256 blocks x 128 threads.
__global__ __launch_bounds__(128) void prep_split(
    const float* __restrict__ x, u16* __restrict__ xh, u16* __restrict__ xl) {
  int tg = blockIdx.x * 128 + threadIdx.x;  // 0..32767
  int kb = tg & 511;
  int m = tg >> 9;
  const float* xp = x + m * K_DIM + kb * 8;
  u16 hs[8], ls[8];
#pragma unroll
  for (int j = 0; j < 8; ++j) {
    float v = xp[j];
    unsigned hv = __float_as_uint(v) & 0xFFFF0000u;  // bf16 truncate (exact)
    float r = v - __uint_as_float(hv);
    hs[j] = (u16)(hv >> 16);
    ls[j] = (u16)(__float_as_uint(r) >> 16);
  }
  int o = kb * (M_DIM * 8) + m * 8;
  *(uint4*)(xh + o) = *(uint4*)hs;
  *(uint4*)(xl + o) = *(uint4*)ls;
}

// ---------------------------------------------------------------------------
// Streaming GEMM v10 — v7 (passing, stable) with ONE structural change:
// 256 blocks of 56-col stripes (was 224 x 64) -> 100% CU coverage (R4/R6
// theory: 224 blocks idle 32 CUs, capping device read BW at ~5.5 TB/s).
// 56 = 3 full 16-col B-frags + 1 half-frag: lanes lnk>=8 of frag 3 clamp
// their W address in-bounds and AND-mask their packed B dword to 0 (+0.0
// bf16, exact). Everything else byte-for-byte v7: full-K blocks, 8 waves
// (2/SIMD), depth-1 reg double-buffer, in-kernel rowsum via ones-B MFMA,
// two-stage LDS k-reduction, fused affine epilogue. No atomics, no big LDS
// (v9's 146KB design killed two containers -> abandoned).
__global__ __launch_bounds__(512, 2) void wqmm(
    const int* __restrict__ W, const u16* __restrict__ xh,
    const u16* __restrict__ xl, const float* __restrict__ scale,
    const float* __restrict__ offset, const float* __restrict__ bias,
    float* __restrict__ out) {
  __shared__ __align__(16) float red[4][64][66];  // 67.6 KB (v7-proven)

  const int t = threadIdx.x;
  const int lane = t & 63;
  const int wv = t >> 6;       // k-eighth, 0..7
  const int quad = lane >> 4;
  const int lnk = lane & 15;
  const int nbase = blockIdx.x * WPB;
  const int k0 = wv * KW;

  // loop-invariant per-lane dword offsets into W; frag 3 is the half-frag:
  // lanes lnk>=8 clamp to cols 48+(lnk&7) (in-bounds dup), masked at pack.
  int laneoff[4];
#pragma unroll
  for (int f = 0; f < 3; ++f)
    laneoff[f] = quad * 8 * N_DIM + nbase + lnk + f * 16;
  laneoff[3] = quad * 8 * N_DIM + nbase + 48 + (lnk & 7);
  const int kmask = (lnk < 8) ? ~0 : 0;  // zero B dwords for dup lanes (f=3)

  const u16* xhp = xh + (size_t)(wv * 64 + quad) * 512 + lnk * 8;
  const u16* xlp = xl + (size_t)(wv * 64 + quad) * 512 + lnk * 8;

  // constant ones B-fragment (bf16 1.0 = 0x3F80) for the rowsum MFMA
  const bf16x8 bones = {(short)0x3F80, (short)0x3F80, (short)0x3F80,
                        (short)0x3F80, (short)0x3F80, (short)0x3F80,
                        (short)0x3F80, (short)0x3F80};

  f32x4 acc[4][4] = {};       // [m-tile][n-frag]
  f32x4 acc1[4] = {};         // [m-tile] rowsum accumulator
  int raw[2][4][8];           // W double buffer (literal indices only)
  bf16x8 abh[2][4], abl[2][4];  // A double buffer

#define LOADW(CC, BUF)                                            \
  do {                                                            \
    _Pragma("unroll") for (int j = 0; j < 8; ++j) {               \
      const int* bj = W + (size_t)(k0 + (CC) * 32 + j) * N_DIM;   \
      _Pragma("unroll") for (int f = 0; f < 4; ++f)               \
          raw[BUF][f][j] = bj[laneoff[f]];                        \
    }                                                             \
  } while (0)

#define LOADA(CC, BUF)                                            \
  do {                                                            \
    const u16* ahc = xhp + (CC) * 2048;                           \
    const u16* alc = xlp + (CC) * 2048;                           \
    _Pragma("unroll") for (int mt = 0; mt < 4; ++mt) {            \
      abh[BUF][mt] = *(const bf16x8*)(ahc + mt * 128);            \
      abl[BUF][mt] = *(const bf16x8*)(alc + mt * 128);            \
    }                                                             \
  } while (0)

#define COMPUTE(CC, BUF)                                                     \
  do {                                                                       \
    bf16x8 bfr[4];                                                           \
    _Pragma("unroll") for (int f = 0; f < 4; ++f) {                          \
      union {                                                                \
        int i4[4];                                                           \
        bf16x8 v;                                                            \
      } u;                                                                   \
      _Pragma("unroll") for (int wd = 0; wd < 4; ++wd) {                     \
        unsigned lo = __float_as_uint((float)raw[BUF][f][2 * wd]);           \
        unsigned hi = __float_as_uint((float)raw[BUF][f][2 * wd + 1]);       \
        /* v_perm_b32: D = {hi[31:16], lo[31:16]} — exact bf16 pack */       \
        u.i4[wd] = (int)__builtin_amdgcn_perm(hi, lo, 0x07060302u);          \
        if (f == 3) u.i4[wd] &= kmask; /* half-frag: dup lanes -> +0.0 */    \
      }                                                                      \
      bfr[f] = u.v;                                                          \
    }                                                                        \
    _Pragma("unroll") for (int mt = 0; mt < 4; ++mt) {                       \
      _Pragma("unroll") for (int f = 0; f < 4; ++f) {                        \
        acc[mt][f] = __builtin_amdgcn_mfma_f32_16x16x32_bf16(                \
            abh[BUF][mt], bfr[f], acc[mt][f], 0, 0, 0);                      \
        acc[mt][f] = __builtin_amdgcn_mfma_f32_16x16x32_bf16(                \
            abl[BUF][mt], bfr[f], acc[mt][f], 0, 0, 0);                      \
      }                                                                      \
      acc1[mt] = __builtin_amdgcn_mfma_f32_16x16x32_bf16(                    \
          abh[BUF][mt], bones, acc1[mt], 0, 0, 0);                           \
      acc1[mt] = __builtin_amdgcn_mfma_f32_16x16x32_bf16(                    \
          abl[BUF][mt], bones, acc1[mt], 0, 0, 0);                           \
    }                                                                        \
  } while (0)

  LOADW(0, 0);
  LOADA(0, 0);
  for (int c = 0; c < WCHUNKS; c += 2) {  // literal buffer indices in body
    LOADW(c + 1, 1);
    LOADA(c + 1, 1);
    COMPUTE(c, 0);
    if (c + 2 < WCHUNKS) {
      LOADW(c + 2, 0);
      LOADA(c + 2, 0);
    }
    COMPUTE(c + 1, 1);
  }
#undef LOADW
#undef LOADA
#undef COMPUTE

  // two-stage intra-block k-reduction (v7-proven):
  // stage 1: waves 0-3 deposit their tile (+ rowsum col 64)
  if (wv < 4) {
#pragma unroll
    for (int f = 0; f < 4; ++f)
#pragma unroll
      for (int mt = 0; mt < 4; ++mt)
#pragma unroll
        for (int r = 0; r < 4; ++r)
          red[wv][mt * 16 + quad * 4 + r][f * 16 + lnk] = acc[mt][f][r];
    if (lnk == 0) {
#pragma unroll
      for (int mt = 0; mt < 4; ++mt)
#pragma unroll
        for (int r = 0; r < 4; ++r)
          red[wv][mt * 16 + quad * 4 + r][64] = acc1[mt][r];
    }
  }
  __syncthreads();
  // stage 2: waves 4-7 accumulate into the matching buffer (disjoint addrs)
  if (wv >= 4) {
#pragma unroll
    for (int f = 0; f < 4; ++f)
#pragma unroll
      for (int mt = 0; mt < 4; ++mt)
#pragma unroll
        for (int r = 0; r < 4; ++r)
          red[wv - 4][mt * 16 + quad * 4 + r][f * 16 + lnk] += acc[mt][f][r];
    if (lnk == 0) {
#pragma unroll
      for (int mt = 0; mt < 4; ++mt)
#pragma unroll
        for (int r = 0; r < 4; ++r)
          red[wv - 4][mt * 16 + quad * 4 + r][64] += acc1[mt][r];
    }
  }
  __syncthreads();

  // fused epilogue over 64 x 56 tile:
  // out = scale*sum + scale*offset*rowsum[m] + bias
#pragma unroll
  for (int i = 0; i < 7; ++i) {
    int idx = t + i * 512;  // 0..3583
    int m = idx / WPB;
    int nc = idx - m * WPB;  // 0..55
    float s = red[0][m][nc] + red[1][m][nc] + red[2][m][nc] + red[3][m][nc];
    float rs = red[0][m][64] + red[1][m][64] + red[2][m][64] + red[3][m][64];
    int n = nbase + nc;
    float sc = scale[n];
    out[(size_t)m * N_DIM + n] = s * sc + sc * offset[n] * rs + bias[n];
  }
}

extern "C" void kernel_launch(void* const* d_in, const int* in_sizes, int n_in,
                              void* d_out, int out_size, void* d_ws,
                              size_t ws_size, hipStream_t stream) {
  const float* x = (const float*)d_in[0];
  const int* W = (const int*)d_in[1];
  const float* scale = (const float*)d_in[2];
  const float* offset = (const float*)d_in[3];
  const float* bias = (const float*)d_in[4];
  float* out = (float*)d_out;

  char* wsb = (char*)d_ws;
  u16* xh = (u16*)wsb;                          // 512 KB
  u16* xl = xh + (size_t)M_DIM * K_DIM;         // 512 KB

  prep_split<<<256, 128, 0, stream>>>(x, xh, xl);
  wqmm<<<NBLKS, 512, 0, stream>>>(W, xh, xl, scale, offset, bias, out);
}

// Round 8
// 331.062 us; speedup vs baseline: 1.0205x; 1.0205x over previous
//
#include <hip/hip_runtime.h>
#include <hip/hip_bf16.h>

#define M_DIM 64
#define K_DIM 4096
#define N_DIM 14336
#define NBLKS 224       // one block per 64 n-cols (v7-proven geometry)
#define KW 512          // k-range per wave (8 waves cover K=4096)
#define WCHUNKS 16      // 32-k chunks per wave

typedef __attribute__((ext_vector_type(8))) short bf16x8;
typedef __attribute__((ext_vector_type(4))) float f32x4;
typedef unsigned short u16;

// ---------------------------------------------------------------------------
// prep v5: truncate x (fp32) to bf16 in MFMA-A-fragment layout
// (elem idx = (k/8)*(64*8) + m*8 + (k%8)). NO hi/lo split (R7 post-mortem:
// error budget shows single-bf16 A adds ~0.1-0.3 output error vs threshold
// 8.16 — the split doubled MFMA count and A traffic for precision nobody
// needed). 256 blocks x 128 threads, pure streaming.
__global__ __launch_bounds__(128) void prep_split(
    const float* __restrict__ x, u16* __restrict__ xh) {
  int tg = blockIdx.x * 128 + threadIdx.x;  // 0..32767
  int kb = tg & 511;
  int m = tg >> 9;
  const float* xp = x + m * K_DIM + kb * 8;
  u16 hs[8];
#pragma unroll
  for (int j = 0; j < 8; ++j)
    hs[j] = (u16)(__float_as_uint(xp[j]) >> 16);  // bf16 truncate
  int o = kb * (M_DIM * 8) + m * 8;
  *(uint4*)(xh + o) = *(uint4*)hs;
}

// ---------------------------------------------------------------------------
// Streaming GEMM v11 — v7's exact proven structure (224 blocks x 64 cols,
// 8 waves 2/SIMD, depth-2 W register prefetch, in-kernel rowsum via ones-B
// MFMA, two-stage LDS k-reduction, fused affine epilogue) with the lo-path
// deleted: 20 MFMA/chunk (was 40), A-fragment traffic halved (112 MB), A
// vmem instruction count halved, ~32 VGPRs freed. W stream (235 MB, 256-B
// sector-aligned runs — the measured local optimum) untouched.
__global__ __launch_bounds__(512, 2) void wqmm(
    const int* __restrict__ W, const u16* __restrict__ xh,
    const float* __restrict__ scale, const float* __restrict__ offset,
    const float* __restrict__ bias, float* __restrict__ out) {
  __shared__ __align__(16) float red[4][64][66];  // 67.6 KB; col 64 = rowsum

  const int t = threadIdx.x;
  const int lane = t & 63;
  const int wv = t >> 6;       // k-eighth, 0..7
  const int quad = lane >> 4;
  const int lnk = lane & 15;
  const int nbase = blockIdx.x * 64;
  const int k0 = wv * KW;

  // loop-invariant per-lane dword offsets into W
  int laneoff[4];
#pragma unroll
  for (int f = 0; f < 4; ++f)
    laneoff[f] = quad * 8 * N_DIM + nbase + lnk + f * 16;

  const u16* xhp = xh + (size_t)(wv * 64 + quad) * 512 + lnk * 8;

  // constant ones B-fragment (bf16 1.0 = 0x3F80) for the rowsum MFMA
  const bf16x8 bones = {(short)0x3F80, (short)0x3F80, (short)0x3F80,
                        (short)0x3F80, (short)0x3F80, (short)0x3F80,
                        (short)0x3F80, (short)0x3F80};

  f32x4 acc[4][4] = {};       // [m-tile][n-frag]
  f32x4 acc1[4] = {};         // [m-tile] rowsum accumulator
  int raw[2][4][8];           // W double buffer (literal indices only)
  bf16x8 abh[2][4];           // A double buffer (bf16-truncated x)

#define LOADW(CC, BUF)                                            \
  do {                                                            \
    _Pragma("unroll") for (int j = 0; j < 8; ++j) {               \
      const int* bj = W + (size_t)(k0 + (CC) * 32 + j) * N_DIM;   \
      _Pragma("unroll") for (int f = 0; f < 4; ++f)               \
          raw[BUF][f][j] = bj[laneoff[f]];                        \
    }                                                             \
  } while (0)

#define LOADA(CC, BUF)                                            \
  do {                                                            \
    const u16* ahc = xhp + (CC) * 2048;                           \
    _Pragma("unroll") for (int mt = 0; mt < 4; ++mt)              \
        abh[BUF][mt] = *(const bf16x8*)(ahc + mt * 128);          \
  } while (0)

#define COMPUTE(CC, BUF)                                                     \
  do {                                                                       \
    bf16x8 bfr[4];                                                           \
    _Pragma("unroll") for (int f = 0; f < 4; ++f) {                          \
      union {                                                                \
        int i4[4];                                                           \
        bf16x8 v;                                                            \
      } u;                                                                   \
      _Pragma("unroll") for (int wd = 0; wd < 4; ++wd) {                     \
        unsigned lo = __float_as_uint((float)raw[BUF][f][2 * wd]);           \
        unsigned hi = __float_as_uint((float)raw[BUF][f][2 * wd + 1]);       \
        /* v_perm_b32: D = {hi[31:16], lo[31:16]} — exact bf16 pack */       \
        u.i4[wd] = (int)__builtin_amdgcn_perm(hi, lo, 0x07060302u);          \
      }                                                                      \
      bfr[f] = u.v;                                                          \
    }                                                                        \
    _Pragma("unroll") for (int mt = 0; mt < 4; ++mt) {                       \
      _Pragma("unroll") for (int f = 0; f < 4; ++f)                          \
        acc[mt][f] = __builtin_amdgcn_mfma_f32_16x16x32_bf16(                \
            abh[BUF][mt], bfr[f], acc[mt][f], 0, 0, 0);                      \
      acc1[mt] = __builtin_amdgcn_mfma_f32_16x16x32_bf16(                    \
          abh[BUF][mt], bones, acc1[mt], 0, 0, 0);                           \
    }                                                                        \
  } while (0)

  LOADW(0, 0);
  LOADA(0, 0);
  for (int c = 0; c < WCHUNKS; c += 2) {  // literal buffer indices in body
    LOADW(c + 1, 1);
    LOADA(c + 1, 1);
    COMPUTE(c, 0);
    if (c + 2 < WCHUNKS) {
      LOADW(c + 2, 0);
      LOADA(c + 2, 0);
    }
    COMPUTE(c + 1, 1);
  }
#undef LOADW
#undef LOADA
#undef COMPUTE

  // two-stage intra-block k-reduction (v7-proven):
  // stage 1: waves 0-3 deposit their tile (+ rowsum col 64)
  if (wv < 4) {
#pragma unroll
    for (int f = 0; f < 4; ++f)
#pragma unroll
      for (int mt = 0; mt < 4; ++mt)
#pragma unroll
        for (int r = 0; r < 4; ++r)
          red[wv][mt * 16 + quad * 4 + r][f * 16 + lnk] = acc[mt][f][r];
    if (lnk == 0) {
#pragma unroll
      for (int mt = 0; mt < 4; ++mt)
#pragma unroll
        for (int r = 0; r < 4; ++r)
          red[wv][mt * 16 + quad * 4 + r][64] = acc1[mt][r];
    }
  }
  __syncthreads();
  // stage 2: waves 4-7 accumulate into the matching buffer (disjoint addrs)
  if (wv >= 4) {
#pragma unroll
    for (int f = 0; f < 4; ++f)
#pragma unroll
      for (int mt = 0; mt < 4; ++mt)
#pragma unroll
        for (int r = 0; r < 4; ++r)
          red[wv - 4][mt * 16 + quad * 4 + r][f * 16 + lnk] += acc[mt][f][r];
    if (lnk == 0) {
#pragma unroll
      for (int mt = 0; mt < 4; ++mt)
#pragma unroll
        for (int r = 0; r < 4; ++r)
          red[wv - 4][mt * 16 + quad * 4 + r][64] += acc1[mt][r];
    }
  }
  __syncthreads();

  // fused epilogue: out = scale*sum + scale*offset*rowsum[m] + bias
#pragma unroll
  for (int i = 0; i < 8; ++i) {
    int idx = t + i * 512;  // linear over 64x64 tile -> coalesced stores
    int m = idx >> 6;
    int nc = idx & 63;
    float s = red[0][m][nc] + red[1][m][nc] + red[2][m][nc] + red[3][m][nc];
    float rs = red[0][m][64] + red[1][m][64] + red[2][m][64] + red[3][m][64];
    int n = nbase + nc;
    float sc = scale[n];
    out[(size_t)m * N_DIM + n] = s * sc + sc * offset[n] * rs + bias[n];
  }
}

extern "C" void kernel_launch(void* const* d_in, const int* in_sizes, int n_in,
                              void* d_out, int out_size, void* d_ws,
                              size_t ws_size, hipStream_t stream) {
  const float* x = (const float*)d_in[0];
  const int* W = (const int*)d_in[1];
  const float* scale = (const float*)d_in[2];
  const float* offset = (const float*)d_in[3];
  const float* bias = (const float*)d_in[4];
  float* out = (float*)d_out;

  u16* xh = (u16*)d_ws;                         // 512 KB

  prep_split<<<256, 128, 0, stream>>>(x, xh);
  wqmm<<<NBLKS, 512, 0, stream>>>(W, xh, scale, offset, bias, out);
}